// Round 9
// baseline (681.892 us; speedup 1.0000x reference)
//
#include <hip/hip_runtime.h>

// Problem constants (fixed by reference): B=2, N=8192, C=80
constexpr int NB = 2;
constexpr int NN = 8192;
constexpr int NC = 80;
constexpr int ROWS = NN + 1;   // mask rows per batch; row NN is an all-zero row
constexpr int NBLK = 512;      // fused grid: 2 blocks/CU -> all co-resident

// d_out layout (floats), in reference return order:
constexpr size_t OFF_BOXES  = 0;
constexpr size_t OFF_SCORES = (size_t)NB * NN * 4;
constexpr size_t OFF_LABELS = OFF_SCORES + (size_t)NB * NN;
constexpr size_t OFF_KEEP   = OFF_LABELS + (size_t)NB * NN;
constexpr size_t OFF_ALL    = OFF_KEEP + (size_t)NB * NN;

// d_ws layout
constexpr size_t WS_KEYS  = 0;                                   // B*N u64
constexpr size_t WS_VBYTE = WS_KEYS + (size_t)NB * NN * 8;       // B*N u8
constexpr size_t WS_ORDER = WS_VBYTE + (size_t)NB * NN;          // B*N i32
constexpr size_t WS_SBOX  = WS_ORDER + (size_t)NB * NN * 4;      // B*N float4
constexpr size_t WS_VBITS = WS_SBOX + (size_t)NB * NN * 16;      // B*128 u64
constexpr size_t WS_MASK  = WS_VBITS + (size_t)NB * 128 * 8;     // B*ROWS*128 u64
constexpr size_t WS_DNM   = WS_MASK + (size_t)NB * ROWS * 128 * 8; // B*128*3*64 u64
constexpr size_t WS_TOTAL = WS_DNM + (size_t)NB * 128 * 3 * 64 * 8;
constexpr int DNM_WORDS = NB * 128 * 3 * 64;

typedef unsigned long long u64;

__device__ unsigned int g_cnt = 0;
__device__ volatile unsigned int g_gen = 0;

// Self-resetting device-scope grid barrier (all NBLK blocks resident by
// construction: 4 waves/block, <=128 VGPR -> >=4 blocks/CU capacity).
__device__ __forceinline__ void grid_sync() {
  __syncthreads();
  if (threadIdx.x == 0) {
    __threadfence();
    unsigned int sense = g_gen;
    if (atomicAdd(&g_cnt, 1u) == (unsigned)NBLK - 1u) {
      atomicExch(&g_cnt, 0u);
      __threadfence();
      atomicAdd((unsigned int*)&g_gen, 1u);
    } else {
      while (g_gen == sense) __builtin_amdgcn_s_sleep(8);
    }
    __threadfence();
  }
  __syncthreads();
}

// lgkmcnt(0)-only barrier: keeps global loads in flight across it.
__device__ inline void lbar() {
  __builtin_amdgcn_s_waitcnt(0xc07f);
  __builtin_amdgcn_s_barrier();
}

__device__ inline u64 readlane64(u64 v, int src) {
  unsigned int lo = (unsigned int)__builtin_amdgcn_readlane((int)(unsigned int)v, src);
  unsigned int hi = (unsigned int)__builtin_amdgcn_readlane((int)(unsigned int)(v >> 32), src);
  return ((u64)hi << 32) | lo;
}

__device__ inline u64 readfirstlane64(u64 v) {
  unsigned int lo = (unsigned int)__builtin_amdgcn_readfirstlane((int)(unsigned int)v);
  unsigned int hi = (unsigned int)__builtin_amdgcn_readfirstlane((int)(unsigned int)(v >> 32));
  return ((u64)hi << 32) | lo;
}

// IoU exactly mirroring the numpy op order; contraction off so f32 rounding
// matches numpy bit-for-bit (keep bits tolerate no error).
__device__ inline float iou_pair(const float4 p, const float4 q) {
#pragma clang fp contract(off)
  float areaA = (p.z - p.x) * (p.w - p.y);
  float areaB = (q.z - q.x) * (q.w - q.y);
  float ix1 = fmaxf(p.x, q.x);
  float iy1 = fmaxf(p.y, q.y);
  float ix2 = fminf(p.z, q.z);
  float iy2 = fminf(p.w, q.w);
  float inter = fmaxf(ix2 - ix1, 0.0f) * fmaxf(iy2 - iy1, 0.0f);
  float uni = areaA + areaB - inter;
  return inter / fmaxf(uni, 1e-9f);
}

__device__ inline float clip01(float v) { return fminf(fmaxf(v, 0.0f), 1.0f); }

// ===== Fused pipeline: decode -> rank -> build -> reduce, one launch =====
__global__ __launch_bounds__(256) void fused_kernel(
    const float* __restrict__ logits, const float4* __restrict__ deltas,
    const float4* __restrict__ anchors, float4* __restrict__ boxes_out,
    float* __restrict__ scores_out, float* __restrict__ labels_out,
    float* __restrict__ keep_out, float* __restrict__ all_out,
    u64* __restrict__ keys, unsigned char* __restrict__ vbyte,
    int* __restrict__ order, float4* __restrict__ sbox,
    u64* __restrict__ vbits, u64* __restrict__ mask, u64* __restrict__ dnm) {
#pragma clang fp contract(off)
  int tid = threadIdx.x, lane = tid & 63, wib = tid >> 6;  // wave in block
  int tg = blockIdx.x * 256 + tid;
  int nth = NBLK * 256;
  int gwave = tg >> 6, nwaves = nth >> 6;

  __shared__ float4 cbs[4][64];     // build slabs (per wave)
  __shared__ u64 s_remv[128];
  __shared__ u64 s_keep[128];
  __shared__ int s_rowlist[2][72];
  __shared__ int s_nk[2];

  // ---------- P1: zero-inits + decode ----------
  for (int z = tg; z < NB * 128; z += nth) vbits[z] = 0ull;
  for (int z = tg; z < DNM_WORDS; z += nth) dnm[z] = 0ull;
  for (int z = tg; z < NB * 128; z += nth) {  // zero row NN per batch
    int b = z >> 7, w = z & 127;
    mask[((size_t)b * ROWS + NN) * 128 + w] = 0ull;
  }
  for (int wid = gwave; wid < NB * NN; wid += nwaves) {
    int n = wid & (NN - 1);
    size_t base = (size_t)wid * NC;
    float x0 = logits[base + lane];
    float sig0 = 1.0f / (1.0f + expf(-x0));
    all_out[base + lane] = sig0;
    float bs = sig0;
    int bidx = lane;
    if (lane < NC - 64) {
      float x1 = logits[base + 64 + lane];
      float sig1 = 1.0f / (1.0f + expf(-x1));
      all_out[base + 64 + lane] = sig1;
      if (sig1 > bs) { bs = sig1; bidx = lane + 64; }
    }
    for (int off = 32; off; off >>= 1) {
      float os = __shfl_xor(bs, off, 64);
      int oi = __shfl_xor(bidx, off, 64);
      if (os > bs || (os == bs && oi < bidx)) { bs = os; bidx = oi; }
    }
    if (lane == 0) {
      float4 d = deltas[wid];
      float4 a = anchors[n];
      float aw = a.z - a.x, ah = a.w - a.y;
      float acx = a.x + 0.5f * aw, acy = a.y + 0.5f * ah;
      float dw = fminf(d.z, 4.0f), dh = fminf(d.w, 4.0f);
      float pcx = d.x * aw + acx;
      float pcy = d.y * ah + acy;
      float pw = expf(dw) * aw;
      float ph = expf(dh) * ah;
      float4 bx;
      bx.x = clip01(pcx - 0.5f * pw);
      bx.y = clip01(pcy - 0.5f * ph);
      bx.z = clip01(pcx + 0.5f * pw);
      bx.w = clip01(pcy + 0.5f * ph);
      boxes_out[wid] = bx;
      scores_out[wid] = bs;
      labels_out[wid] = (float)bidx;
      float bw = bx.z - bx.x, bh = bx.w - bx.y;
      bool valid = (bs > 0.5f) && (bw > 0.01f) && (bh > 0.01f) &&
                   (bw < 0.99f) && (bh < 0.99f);
      vbyte[wid] = valid ? 1 : 0;
      keys[wid] = ((u64)__float_as_uint(bs) << 32) | (unsigned int)(NN - 1 - n);
    }
  }
  grid_sync();

  // ---------- P2: rank sort (keys unique -> permutation) ----------
  for (int row = gwave; row < NB * NN; row += nwaves) {
    int b = row >> 13, i = row & (NN - 1);
    const u64* kb = keys + (size_t)b * NN;
    u64 myk = kb[i];
    int cnt = 0;
    for (int j = lane; j < NN; j += 64) cnt += (kb[j] > myk) ? 1 : 0;
    for (int off = 32; off; off >>= 1) cnt += __shfl_xor(cnt, off, 64);
    if (lane == 0) {
      int rank = cnt;
      order[(size_t)b * NN + rank] = i;
      sbox[(size_t)b * NN + rank] = boxes_out[(size_t)b * NN + i];
      if (vbyte[(size_t)b * NN + i])
        atomicOr(&vbits[b * 128 + (rank >> 6)], 1ull << (rank & 63));
    }
  }
  grid_sync();

  // ---------- P3: build suppression matrix (upper triangle, 64x64 tiles) ----
  for (int t = gwave; t < NB * 128 * 128; t += nwaves) {
    int b = t >> 14, r = t & 16383, by = r >> 7, bx = r & 127;
    if (bx < by) continue;
    cbs[wib][lane] = sbox[(size_t)b * NN + bx * 64 + lane];
    int i = by * 64 + lane;
    float4 rb = sbox[(size_t)b * NN + i];
    u64 word = 0;
    int j0 = (bx == by) ? lane + 1 : 0;
    for (int jj = j0; jj < 64; ++jj)
      if (iou_pair(rb, cbs[wib][jj]) > 0.5f) word |= 1ull << jj;
    mask[((size_t)b * ROWS + i) * 128 + bx] = word;
    int dq = bx - by;
    if (dq < 3) dnm[(((size_t)b * 128 + by) * 3 + dq) * 64 + lane] = word;
  }
  grid_sync();

  // ---------- P4: greedy reduce (v6 structure), blocks 0..NB-1 only -------
  if (blockIdx.x >= NB) return;
  int b = blockIdx.x;
  const u64* mb = mask + (size_t)b * ROWS * 128;
  const u64* dn = dnm + (size_t)b * 128 * 3 * 64;

  for (int w = tid; w < 128; w += 256) s_remv[w] = 0ull;
  if (tid < 2) s_nk[tid] = 0;
  if (tid < 144) s_rowlist[tid / 72][tid % 72] = NN;

  u64 va = 0, vb2 = 0;
  u64 dA = 0, nA = 0, mA = 0, dB = 0, nB = 0, mB = 0;
  u64 dC = 0, nC = 0, mC = 0, dD = 0, nD = 0, mD = 0;
  if (wib == 0) {
    va = vbits[b * 128 + 2 * lane];
    vb2 = vbits[b * 128 + 2 * lane + 1];
    const u64* r0 = dn + lane;           // chunk 0
    dA = r0[0]; nA = r0[64]; mA = r0[128];
    const u64* r1 = dn + 3 * 64 + lane;  // chunk 1
    dB = r1[0]; nB = r1[64]; mB = r1[128];
  }
  ulonglong2 T[8];
#pragma unroll
  for (int k = 0; k < 8; ++k) T[k] = ulonglong2{0, 0};
  int w0i = 2 * lane, w1i = 2 * lane + 1;
  __syncthreads();

  auto serial_body = [&](int c, u64 dcur, u64 ncur, u64 mcur, u64& dnew,
                         u64& nnew, u64& mnew) {
    if (c + 2 < 128) {
      const u64* rp = dn + (size_t)(c + 2) * 3 * 64 + lane;
      dnew = rp[0]; nnew = rp[64]; mnew = rp[128];
    } else {
      dnew = 0; nnew = 0; mnew = 0;
    }
    int par = c & 1;
    u64 rm = s_remv[c];
    u64 vbw = readlane64((c & 1) ? vb2 : va, c >> 1);
    u64 cand = readfirstlane64(vbw & ~rm);
    u64 kept = 0;
    while (cand) {  // scalar loop, one iter per kept box
      int bi = (int)__builtin_ctzll(cand);
      u64 rd = readlane64(dcur, bi);
      kept |= 1ull << bi;
      cand = (cand - 1) & cand & ~rd;
    }
    bool isk = (kept >> lane) & 1;
    if (c + 1 < 128 && isk && ncur) atomicOr(&s_remv[c + 1], ncur);
    if (c + 2 < 128 && isk && mcur) atomicOr(&s_remv[c + 2], mcur);
    s_rowlist[par][lane] = NN;
    if (isk) {
      int pos = __popcll(kept & ((1ull << lane) - 1ull));
      s_rowlist[par][pos] = c * 64 + lane;
    }
    if (lane == 0) {
      s_keep[c] = kept;
      s_nk[par] = __popcll(kept);
    }
  };

  auto bg_body = [&](int c) {
    // consume T (rows of chunk c-2, issued at c-1) into words > c
    u64 ax = T[0].x | T[1].x | T[2].x | T[3].x | T[4].x | T[5].x | T[6].x | T[7].x;
    u64 ay = T[0].y | T[1].y | T[2].y | T[3].y | T[4].y | T[5].y | T[6].y | T[7].y;
    if (w0i > c && ax) atomicOr(&s_remv[w0i], ax);
    if (w1i > c && ay) atomicOr(&s_remv[w1i], ay);
    // issue rows of chunk c-1 (consumed at c+1 into words > c+1)
    int nkp = s_nk[(c - 1) & 1];
#pragma unroll
    for (int k = 0; k < 8; ++k) T[k] = ulonglong2{0, 0};
    if (nkp > 0 && w1i > c + 1) {
      const int* rl = s_rowlist[(c - 1) & 1];
#pragma unroll
      for (int k = 0; k < 8; ++k) {
        int r = rl[(wib - 1) + 3 * k];  // waves 1..3 cover slots 0..23
        T[k] = *(const ulonglong2*)(mb + (size_t)r * 128 + w0i);
      }
      if (nkp > 24) {  // rare overflow: synchronous, deposits words > c+1
        u64 ox = 0, oy = 0;
        for (int s = 24 + (wib - 1); s < nkp; s += 3) {
          ulonglong2 v = *(const ulonglong2*)(mb + (size_t)rl[s] * 128 + w0i);
          ox |= v.x; oy |= v.y;
        }
        if (w0i > c + 1 && ox) atomicOr(&s_remv[w0i], ox);
        if (w1i > c + 1 && oy) atomicOr(&s_remv[w1i], oy);
      }
    }
  };

  for (int c = 0; c < 128; c += 4) {
    if (wib == 0) serial_body(c, dA, nA, mA, dC, nC, mC);
    else bg_body(c);
    lbar();
    if (wib == 0) serial_body(c + 1, dB, nB, mB, dD, nD, mD);
    else bg_body(c + 1);
    lbar();
    if (wib == 0) serial_body(c + 2, dC, nC, mC, dA, nA, mA);
    else bg_body(c + 2);
    lbar();
    if (wib == 0) serial_body(c + 3, dD, nD, mD, dB, nB, mB);
    else bg_body(c + 3);
    lbar();
  }

  for (int p = tid; p < NN; p += 256) {
    int orig = order[(size_t)b * NN + p];
    keep_out[(size_t)b * NN + orig] =
        ((s_keep[p >> 6] >> (p & 63)) & 1) ? 1.0f : 0.0f;
  }
}

// ===== Fallback path (ws too small for the mask): previous kernels =====
__global__ __launch_bounds__(256) void decode_kernel(
    const float* __restrict__ logits, const float4* __restrict__ deltas,
    const float4* __restrict__ anchors, float4* __restrict__ boxes_out,
    float* __restrict__ scores_out, float* __restrict__ labels_out,
    float* __restrict__ all_out, u64* __restrict__ keys,
    unsigned char* __restrict__ vbyte, u64* __restrict__ vbits) {
#pragma clang fp contract(off)
  if (blockIdx.x == 0 && threadIdx.x < NB * 128) vbits[threadIdx.x] = 0ull;
  int wid = (blockIdx.x * 256 + threadIdx.x) >> 6;
  int lane = threadIdx.x & 63;
  int n = wid & (NN - 1);
  size_t base = (size_t)wid * NC;
  float x0 = logits[base + lane];
  float sig0 = 1.0f / (1.0f + expf(-x0));
  all_out[base + lane] = sig0;
  float bs = sig0;
  int bidx = lane;
  if (lane < NC - 64) {
    float x1 = logits[base + 64 + lane];
    float sig1 = 1.0f / (1.0f + expf(-x1));
    all_out[base + 64 + lane] = sig1;
    if (sig1 > bs) { bs = sig1; bidx = lane + 64; }
  }
  for (int off = 32; off; off >>= 1) {
    float os = __shfl_xor(bs, off, 64);
    int oi = __shfl_xor(bidx, off, 64);
    if (os > bs || (os == bs && oi < bidx)) { bs = os; bidx = oi; }
  }
  if (lane == 0) {
    float4 d = deltas[wid];
    float4 a = anchors[n];
    float aw = a.z - a.x, ah = a.w - a.y;
    float acx = a.x + 0.5f * aw, acy = a.y + 0.5f * ah;
    float dw = fminf(d.z, 4.0f), dh = fminf(d.w, 4.0f);
    float pcx = d.x * aw + acx, pcy = d.y * ah + acy;
    float pw = expf(dw) * aw, ph = expf(dh) * ah;
    float4 bx;
    bx.x = clip01(pcx - 0.5f * pw);
    bx.y = clip01(pcy - 0.5f * ph);
    bx.z = clip01(pcx + 0.5f * pw);
    bx.w = clip01(pcy + 0.5f * ph);
    boxes_out[wid] = bx;
    scores_out[wid] = bs;
    labels_out[wid] = (float)bidx;
    float bw = bx.z - bx.x, bh = bx.w - bx.y;
    bool valid = (bs > 0.5f) && (bw > 0.01f) && (bh > 0.01f) &&
                 (bw < 0.99f) && (bh < 0.99f);
    vbyte[wid] = valid ? 1 : 0;
    keys[wid] = ((u64)__float_as_uint(bs) << 32) | (unsigned int)(NN - 1 - n);
  }
}

__global__ __launch_bounds__(1024) void rank_kernel(
    const u64* __restrict__ keys, const float4* __restrict__ boxes,
    const unsigned char* __restrict__ vbyte, int* __restrict__ order,
    float4* __restrict__ sbox, u64* __restrict__ vbits) {
  int b = blockIdx.y;
  int r = threadIdx.x & 255, q = threadIdx.x >> 8;
  int i = blockIdx.x * 256 + r;
  const u64* kb = keys + (size_t)b * NN;
  u64 myk = kb[i];
  int cnt = 0;
  int j0 = q * (NN / 4), j1 = j0 + NN / 4;
#pragma unroll 8
  for (int j = j0; j < j1; ++j) cnt += (kb[j] > myk) ? 1 : 0;
  __shared__ unsigned short part[4][256];
  part[q][r] = (unsigned short)cnt;
  __syncthreads();
  if (threadIdx.x < 256) {
    int rank = part[0][r] + part[1][r] + part[2][r] + part[3][r];
    order[(size_t)b * NN + rank] = i;
    sbox[(size_t)b * NN + rank] = boxes[(size_t)b * NN + i];
    if (vbyte[(size_t)b * NN + i])
      atomicOr(&vbits[b * 128 + (rank >> 6)], 1ull << (rank & 63));
  }
}

__global__ __launch_bounds__(1024) void nms_fallback(
    const float4* __restrict__ sbox, const u64* __restrict__ vbits,
    const int* __restrict__ order, float* __restrict__ keep_out) {
  int b = blockIdx.x, tid = threadIdx.x;
  __shared__ u64 dead[128];
  __shared__ int s_next;
  __shared__ float4 s_box;
  for (int w = tid; w < 128; w += 1024) dead[w] = ~vbits[b * 128 + w];
  for (int p = tid; p < NN; p += 1024)
    keep_out[(size_t)b * NN + order[(size_t)b * NN + p]] = 0.0f;
  __syncthreads();
  int i = 0;
  while (true) {
    if (tid == 0) {
      int nxt = NN;
      int w = i >> 6;
      u64 live = ~dead[w] & (~0ull << (i & 63));
      while (true) {
        if (live) { nxt = w * 64 + __builtin_ctzll(live); break; }
        if (++w >= 128) break;
        live = ~dead[w];
      }
      s_next = nxt;
      if (nxt < NN) {
        s_box = sbox[(size_t)b * NN + nxt];
        keep_out[(size_t)b * NN + order[(size_t)b * NN + nxt]] = 1.0f;
      }
    }
    __syncthreads();
    i = s_next;
    if (i >= NN) break;
    float4 kb = s_box;
    for (int j = i + 1 + tid; j < NN; j += 1024) {
      if (iou_pair(kb, sbox[(size_t)b * NN + j]) > 0.5f)
        atomicOr(&dead[j >> 6], 1ull << (j & 63));
    }
    __syncthreads();
    i = i + 1;
  }
}

extern "C" void kernel_launch(void* const* d_in, const int* in_sizes, int n_in,
                              void* d_out, int out_size, void* d_ws, size_t ws_size,
                              hipStream_t stream) {
  const float* logits = (const float*)d_in[0];
  const float4* deltas = (const float4*)d_in[1];
  const float4* anchors = (const float4*)d_in[2];
  float* out = (float*)d_out;
  float4* boxes_out = (float4*)(out + OFF_BOXES);
  float* scores_out = out + OFF_SCORES;
  float* labels_out = out + OFF_LABELS;
  float* keep_out = out + OFF_KEEP;
  float* all_out = out + OFF_ALL;

  char* ws = (char*)d_ws;
  u64* keys = (u64*)(ws + WS_KEYS);
  unsigned char* vbyte = (unsigned char*)(ws + WS_VBYTE);
  int* order = (int*)(ws + WS_ORDER);
  float4* sbox = (float4*)(ws + WS_SBOX);
  u64* vbits = (u64*)(ws + WS_VBITS);
  u64* mask = (u64*)(ws + WS_MASK);
  u64* dnm = (u64*)(ws + WS_DNM);

  if (ws_size >= WS_TOTAL) {
    fused_kernel<<<dim3(NBLK), dim3(256), 0, stream>>>(
        logits, deltas, anchors, boxes_out, scores_out, labels_out, keep_out,
        all_out, keys, vbyte, order, sbox, vbits, mask, dnm);
  } else {
    decode_kernel<<<dim3(NB * NN / 4), dim3(256), 0, stream>>>(
        logits, deltas, anchors, boxes_out, scores_out, labels_out, all_out,
        keys, vbyte, vbits);
    rank_kernel<<<dim3(NN / 256, NB), dim3(1024), 0, stream>>>(
        keys, (const float4*)boxes_out, vbyte, order, sbox, vbits);
    nms_fallback<<<dim3(NB), dim3(1024), 0, stream>>>(sbox, vbits, order,
                                                      keep_out);
  }
}